// Round 6
// baseline (116.753 us; speedup 1.0000x reference)
//
#include <hip/hip_runtime.h>

#define N_NODES 50000
#define N_EDGES 800000
#define N_FEATS 64
#define EB4     (N_EDGES / 4)               // 200000 int4 groups
#define NBUCK   256                          // destination buckets == grid size
#define BRANGE  196                          // nodes per bucket: 256*196 >= 50000
#define ZSTRIDE 208                          // BRANGE padded to 64B lines: z line owned by ONE block
#define NTHR    1024
#define CHUNK   ((EB4 + NBUCK - 1) / NBUCK)  // 782 int4 groups per block
#define CELLCAP 48                           // records per (bucket,block) cell; P(overflow)~1e-13
#define RLMAX   4096                         // compacted records per bucket (mean 3136, +17 sigma)
#define MAGICK(k) (0x9E3779B9u + ((unsigned)(k) << 8))

__device__ __forceinline__ void st_agent(float* p, float v) {
    __hip_atomic_store(p, v, __ATOMIC_RELAXED, __HIP_MEMORY_SCOPE_AGENT);
}
__device__ __forceinline__ void st_agent_u(unsigned* p, unsigned v) {
    __hip_atomic_store(p, v, __ATOMIC_RELAXED, __HIP_MEMORY_SCOPE_AGENT);
}
__device__ __forceinline__ unsigned ld_agent_u(const unsigned* p) {
    return __hip_atomic_load(p, __ATOMIC_RELAXED, __HIP_MEMORY_SCOPE_AGENT);
}
__device__ __forceinline__ unsigned long long ld_agent_u64(const unsigned long long* p) {
    return __hip_atomic_load(p, __ATOMIC_RELAXED, __HIP_MEMORY_SCOPE_AGENT);
}

// Memset-free grid barrier: each block STORES a magic value to its own slot
// (equality check -> no zero-init needed; workspace poison cannot collide with
// the magic). Pollers: 256 threads each sc1-load one slot, block-wide
// __syncthreads_count until all match. Correctness: __syncthreads() drains
// vmcnt before s_barrier (HIP semantics), so all of this block's sc1 data
// stores are at the L3 coherence point before the flag store issues.
// All 256 blocks are co-resident (256 blocks / 256 CUs, 16 waves, ~21 KB LDS),
// so spinning is deadlock-free with a plain launch.
__device__ __forceinline__ void gbar(unsigned* bars, int k) {
    const unsigned magic = MAGICK(k);
    unsigned* slots = bars + k * NBUCK;
    __syncthreads();
    if (threadIdx.x == 0) st_agent_u(&slots[blockIdx.x], magic);
    int n;
    do {
        __builtin_amdgcn_s_sleep(2);
        unsigned v = (threadIdx.x < NBUCK) ? ld_agent_u(&slots[threadIdx.x]) : magic;
        n = __syncthreads_count(v == magic);
    } while (n < NTHR);
}

// Gather own bucket's compacted records (LDS) against zin. CACHED zin reads:
// each z buffer is read in exactly one hop and its 64B lines are single-owner
// (ZSTRIDE pad), so no stale-L2 hazard; ~30x L2 line reuse across the 32
// blocks of an XCD (R4-proven).
__device__ __forceinline__ void gather(const unsigned* recs_l, int sz,
                                       const float* __restrict__ zin,
                                       float* s_acc) {
    const int t = threadIdx.x;
    const int sz4 = sz >> 2;
    const uint4* rl4 = (const uint4*)recs_l;
    for (int e = t; e < sz4; e += NTHR) {
        const uint4 r = rl4[e];
        const float v0 = zin[r.x & 0xFFFFu];
        const float v1 = zin[r.y & 0xFFFFu];
        const float v2 = zin[r.z & 0xFFFFu];
        const float v3 = zin[r.w & 0xFFFFu];
        atomicAdd(&s_acc[r.x >> 16], v0);
        atomicAdd(&s_acc[r.y >> 16], v1);
        atomicAdd(&s_acc[r.z >> 16], v2);
        atomicAdd(&s_acc[r.w >> 16], v3);
    }
    if (t < (sz & 3)) {
        const unsigned r = recs_l[(sz4 << 2) + t];
        atomicAdd(&s_acc[r >> 16], zin[r & 0xFFFFu]);
    }
}

// One kernel, one dispatch: bucketize + prep + 3 hops, 4 magic barriers.
// Block b owns bucket b (nodes [b*196, b*196+196)).
// Record exchange via fixed per-(bucket,block) cells: no gcur atomics, no
// prefix-scan/sort on the writer side, contiguous 48 KB readback per reader.
// Record = (local_dest << 16) | psrc, psrc = src + 12*(src/196) < 53060.
__global__ void __launch_bounds__(NTHR) k_fused(
    const float* __restrict__ x, const int* __restrict__ ei,
    const float* __restrict__ w, const float* __restrict__ bptr,
    float* __restrict__ out,
    unsigned* __restrict__ bars, unsigned* __restrict__ cnt,
    unsigned* __restrict__ recs,
    float* __restrict__ zA, float* __restrict__ zB, float* __restrict__ zC)
{
    __shared__ unsigned recs_l[RLMAX];   // 16 KB compacted record cache
    __shared__ int      s_deg[NBUCK];    // writer histogram -> reader degree
    __shared__ unsigned s_val[NBUCK];    // reader cell counts
    __shared__ int      s_off[NBUCK];    // exclusive prefix of cell counts
    __shared__ int      s_wsum[4];
    __shared__ int      s_total;
    __shared__ float    s_dinv[BRANGE];
    __shared__ float    s_z[BRANGE];
    __shared__ float    s_acc[BRANGE];

    const int t = threadIdx.x;
    const int blk = blockIdx.x;
    const int* row = ei;               // sources
    const int* col = ei + N_EDGES;     // destinations

    // ---------- phase 1: bucketize into cells ----------
    if (t < NBUCK) s_deg[t] = 0;       // role 1: per-bucket histogram
    __syncthreads();

    const int g = blk * CHUNK + t;
    const bool valid = (t < CHUNK) && (g < EB4);
    int4 c4, r4;
    int bk0, bk1, bk2, bk3, rk0, rk1, rk2, rk3;
    if (valid) {
        c4 = ((const int4*)col)[g];
        r4 = ((const int4*)row)[g];
        bk0 = c4.x / BRANGE; rk0 = atomicAdd(&s_deg[bk0], 1);
        bk1 = c4.y / BRANGE; rk1 = atomicAdd(&s_deg[bk1], 1);
        bk2 = c4.z / BRANGE; rk2 = atomicAdd(&s_deg[bk2], 1);
        bk3 = c4.w / BRANGE; rk3 = atomicAdd(&s_deg[bk3], 1);
    }

    // raw matvec (X @ W^T, no dinv yet): independent of the sort; overlaps
    // the LDS-atomic latency above. 4 lanes per node, 4x float4 each.
    const int ln = t >> 2;
    const int pp = t & 3;
    const int node = blk * BRANGE + ln;
    float mv = 0.0f;
    if (ln < BRANGE && node < N_NODES) {
        const float4* xr = (const float4*)(x + (size_t)node * N_FEATS + pp * 16);
        const float4* wr = (const float4*)(w + pp * 16);
        #pragma unroll
        for (int k = 0; k < 4; k++) {
            const float4 v = xr[k];
            const float4 q = wr[k];
            mv += v.x * q.x + v.y * q.y + v.z * q.z + v.w * q.w;
        }
        mv += __shfl_xor(mv, 1);
        mv += __shfl_xor(mv, 2);
        if (pp == 0) s_z[ln] = mv;     // park raw matvec (dinv applied later)
    }
    __syncthreads();                   // all rank atomics done

    // publish cell counts (clamped), then recycle s_deg as degree counters
    if (t < NBUCK) {
        st_agent_u(&cnt[t * NBUCK + blk], (unsigned)min(s_deg[t], CELLCAP));
        s_deg[t] = 0;                  // role 2: degree (same thread owns slot)
    }

    // scattered 4B record stores straight to cells (fire-and-forget sc1;
    // R0/R1 measured scatter-vs-sorted streamout at only ~3us -> not worth
    // the sort machinery it replaced)
    if (valid) {
        const int cc[4] = {c4.x, c4.y, c4.z, c4.w};
        const int rr[4] = {r4.x, r4.y, r4.z, r4.w};
        const int bb[4] = {bk0, bk1, bk2, bk3};
        const int kk[4] = {rk0, rk1, rk2, rk3};
        #pragma unroll
        for (int i = 0; i < 4; i++) {
            if (kk[i] < CELLCAP) {
                const unsigned src = (unsigned)rr[i];
                const unsigned psrc = src + 12u * (src / (unsigned)BRANGE);
                const unsigned rec = ((unsigned)(cc[i] - bb[i] * BRANGE) << 16) | psrc;
                st_agent_u(&recs[(size_t)(bb[i] * NBUCK + blk) * CELLCAP + kk[i]], rec);
            }
        }
    }

    gbar(bars, 0);   // all cells + counts at coherence point

    // ---------- phase 2: readback + degree + dinv + zA publish ----------
    // counts (1 KB contiguous) and records (48 KB contiguous) issued together;
    // record loads' L3 latency overlaps the count scan below.
    const int j   = t >> 2;            // my cell
    const int sub = t & 3;             // my 12-record chunk within the cell
    unsigned long long q0, q1, q2, q3, q4, q5;
    {
        const unsigned long long* rp = (const unsigned long long*)
            (recs + (size_t)(blk * NBUCK + j) * CELLCAP + sub * 12);
        q0 = ld_agent_u64(&rp[0]); q1 = ld_agent_u64(&rp[1]);
        q2 = ld_agent_u64(&rp[2]); q3 = ld_agent_u64(&rp[3]);
        q4 = ld_agent_u64(&rp[4]); q5 = ld_agent_u64(&rp[5]);
    }
    if (t < NBUCK)
        s_val[t] = min(ld_agent_u(&cnt[blk * NBUCK + t]), (unsigned)CELLCAP);
    __syncthreads();

    // exclusive prefix over 256 cell counts (4 waves, shuffle scan)
    if (t < NBUCK) {
        const int lane = t & 63;
        const int c = (int)s_val[t];
        int v = c;
        #pragma unroll
        for (int d = 1; d < 64; d <<= 1) {
            int tmp = __shfl_up(v, d);
            if (lane >= d) v += tmp;
        }
        if (lane == 63) s_wsum[t >> 6] = v;
        s_off[t] = v - c;
    }
    __syncthreads();
    if (t < NBUCK) {
        const int w4 = t >> 6;
        int base = 0;
        #pragma unroll
        for (int i = 0; i < 3; i++) if (i < w4) base += s_wsum[i];
        s_off[t] += base;
        if (t == 0) s_total = s_wsum[0] + s_wsum[1] + s_wsum[2] + s_wsum[3];
    }
    __syncthreads();

    // compact my chunk's valid records into recs_l + degree on the fly
    {
        const int cj  = (int)s_val[j];
        const int nv  = min(max(cj - sub * 12, 0), 12);
        const int pos = s_off[j] + min(sub * 12, cj);
        unsigned long long qq[6] = {q0, q1, q2, q3, q4, q5};
        #pragma unroll
        for (int i = 0; i < 12; i++) {
            if (i < nv) {
                const unsigned rec = (i & 1) ? (unsigned)(qq[i >> 1] >> 32)
                                             : (unsigned)qq[i >> 1];
                if (pos + i < RLMAX) recs_l[pos + i] = rec;
                atomicAdd(&s_deg[rec >> 16], 1);
            }
        }
    }
    const int sz = min(s_total, RLMAX);
    __syncthreads();

    if (t < BRANGE) {
        const float d = rsqrtf((float)(s_deg[t] + 1));  // +1 self loop
        s_dinv[t] = d;
        s_acc[t] = 0.0f;               // hop-1 accumulator pre-zeroed here
        const int nd = blk * BRANGE + t;
        if (nd < N_NODES) {
            const float zv = d * s_z[t];
            s_z[t] = zv;                               // own z in LDS
            st_agent(&zA[blk * ZSTRIDE + t], zv);      // publish padded
        }
    }

    gbar(bars, 1);   // zA visible

    // ---------- hop 1: zA -> zB ----------
    gather(recs_l, sz, zA, s_acc);
    __syncthreads();
    if (t < BRANGE) {
        const int nd = blk * BRANGE + t;
        if (nd < N_NODES) {
            const float d = s_dinv[t];
            const float nz = d * d * (s_z[t] + s_acc[t]);
            s_z[t] = nz;
            st_agent(&zB[blk * ZSTRIDE + t], nz);
        }
        s_acc[t] = 0.0f;               // re-zero for hop 2 (same thread owns)
    }
    gbar(bars, 2);

    // ---------- hop 2: zB -> zC ----------
    gather(recs_l, sz, zB, s_acc);
    __syncthreads();
    if (t < BRANGE) {
        const int nd = blk * BRANGE + t;
        if (nd < N_NODES) {
            const float d = s_dinv[t];
            const float nz = d * d * (s_z[t] + s_acc[t]);
            s_z[t] = nz;
            st_agent(&zC[blk * ZSTRIDE + t], nz);
        }
        s_acc[t] = 0.0f;               // re-zero for hop 3
    }
    gbar(bars, 3);

    // ---------- hop 3: zC -> out ----------
    gather(recs_l, sz, zC, s_acc);
    __syncthreads();
    if (t < BRANGE) {
        const int nd = blk * BRANGE + t;
        if (nd < N_NODES)
            out[nd] = s_dinv[t] * (s_z[t] + s_acc[t]) + bptr[0];
    }
}

// ---------------- launch ----------------

extern "C" void kernel_launch(void* const* d_in, const int* in_sizes, int n_in,
                              void* d_out, int out_size, void* d_ws, size_t ws_size,
                              hipStream_t stream) {
    const float* x  = (const float*)d_in[0];   // [N, 64]
    const int*   ei = (const int*)d_in[1];     // [2, E]
    const float* W  = (const float*)d_in[2];   // [1, 64]
    const float* b  = (const float*)d_in[3];   // [1]
    float* out = (float*)d_out;                // [N]

    // ws: bars[4*256] | cnt[256*256] | recs[65536*48 u32 = 12.6 MB] | zA|zB|zC
    unsigned* bars = (unsigned*)d_ws;
    unsigned* cnt  = bars + 4 * NBUCK;
    unsigned* recs = cnt + NBUCK * NBUCK;
    float*    zA   = (float*)(recs + (size_t)NBUCK * NBUCK * CELLCAP);
    float*    zB   = zA + (size_t)NBUCK * ZSTRIDE;
    float*    zC   = zB + (size_t)NBUCK * ZSTRIDE;

    // Single dispatch, no memset: barriers use store-magic equality flags
    // (poison-tolerant), cells carry explicit counts, z buffers fully written
    // before read. 256 blocks x 16 waves co-resident on 256 CUs.
    k_fused<<<dim3(NBUCK), dim3(NTHR), 0, stream>>>(
        x, ei, W, b, out, bars, cnt, recs, zA, zB, zC);
}

// Round 7
// 101.453 us; speedup vs baseline: 1.1508x; 1.1508x over previous
//
#include <hip/hip_runtime.h>

#define N_NODES 50000
#define N_EDGES 800000
#define N_FEATS 64
#define EB4     (N_EDGES / 4)               // 200000 int4 groups
#define NBUCK   256                          // destination buckets
#define BRANGE  196                          // nodes per bucket: 256*196 >= 50000
#define CAPB    4096                         // records per bucket (mean 3136, +17 sigma)
#define NTHR    1024
#define CHUNK   ((EB4 + NBUCK - 1) / NBUCK)  // 782 int4 groups per block
#define MAXREC  (CHUNK * 4)                  // 3128 records max per block
#define MVBASE  784                          // matvec threads [784, 784+196): disjoint from edge threads (<782)

// Sort buffers: 25 KB, only live in k_bucketize.
struct SmemSort { unsigned buf[MAXREC]; unsigned adr[MAXREC]; };

// ---------------- kernels ----------------

// Bucketize (R1-proven local counting sort -> compact sorted stream-out) with
// the X @ W^T matvec folded onto otherwise-idle threads: its 12.8 MB x-read
// (the largest traffic item) overlaps the LDS-atomic histogram + scan instead
// of serializing inside k_prep. Record = (local_dest << 16) | src.
__global__ void __launch_bounds__(NTHR) k_bucketize(
    const int* __restrict__ row, const int* __restrict__ col,
    const float* __restrict__ x, const float* __restrict__ w,
    int* __restrict__ gcur, unsigned* __restrict__ recs,
    float* __restrict__ mv)
{
    __shared__ SmemSort u;
    __shared__ int s_cnt[NBUCK];
    __shared__ int s_off[NBUCK];
    __shared__ int s_wsum[4];
    __shared__ int s_total;

    const int t = threadIdx.x;
    const int blk = blockIdx.x;

    if (t < NBUCK) s_cnt[t] = 0;
    __syncthreads();

    const int g = blk * CHUNK + t;
    const bool valid = (t < CHUNK) && (g < EB4);
    int4 c4, r4;
    int bk0, bk1, bk2, bk3, rk0, rk1, rk2, rk3;
    if (valid) {
        c4 = ((const int4*)col)[g];
        r4 = ((const int4*)row)[g];
        bk0 = c4.x / BRANGE; rk0 = atomicAdd(&s_cnt[bk0], 1);
        bk1 = c4.y / BRANGE; rk1 = atomicAdd(&s_cnt[bk1], 1);
        bk2 = c4.z / BRANGE; rk2 = atomicAdd(&s_cnt[bk2], 1);
        bk3 = c4.w / BRANGE; rk3 = atomicAdd(&s_cnt[bk3], 1);
    }

    // matvec on threads [784, 980): one thread per owned node, 16x float4.
    // These threads have no edge/histogram work -> true wave-level overlap.
    {
        const int un = t - MVBASE;
        const int node = blk * BRANGE + un;
        if (un >= 0 && un < BRANGE && node < N_NODES) {
            const float4* xr = (const float4*)(x + (size_t)node * N_FEATS);
            const float4* wr = (const float4*)w;
            float a = 0.0f;
            #pragma unroll
            for (int k = 0; k < N_FEATS / 4; k++) {
                const float4 v = xr[k];
                const float4 q = wr[k];
                a += v.x * q.x + v.y * q.y + v.z * q.z + v.w * q.w;
            }
            mv[node] = a;              // raw; dinv applied in k_prep
        }
    }
    __syncthreads();

    // 256-entry exclusive prefix sum (4 waves, shuffle scan)
    if (t < NBUCK) {
        const int lane = t & 63;
        const int cnt = s_cnt[t];
        int val = cnt;
        #pragma unroll
        for (int d = 1; d < 64; d <<= 1) {
            int tmp = __shfl_up(val, d);
            if (lane >= d) val += tmp;
        }
        if (lane == 63) s_wsum[t >> 6] = val;
        s_off[t] = val - cnt;
    }
    __syncthreads();
    if (t < NBUCK) {
        const int w4 = t >> 6;
        int base = 0;
        #pragma unroll
        for (int i = 0; i < 3; i++) if (i < w4) base += s_wsum[i];
        s_off[t] += base;
        const int cnt = s_cnt[t];
        s_cnt[t] = cnt ? atomicAdd(&gcur[t], cnt) : 0;   // global run base
        if (t == 0) s_total = s_wsum[0] + s_wsum[1] + s_wsum[2] + s_wsum[3];
    }
    __syncthreads();

    // scatter records into LDS bucket-major with final global addresses
    if (valid) {
        const int cc[4] = {c4.x, c4.y, c4.z, c4.w};
        const int rr[4] = {r4.x, r4.y, r4.z, r4.w};
        const int bb[4] = {bk0, bk1, bk2, bk3};
        const int kk[4] = {rk0, rk1, rk2, rk3};
        #pragma unroll
        for (int i = 0; i < 4; i++) {
            const int b = bb[i];
            const int p = s_off[b] + kk[i];
            const int slot = s_cnt[b] + kk[i];
            u.buf[p] = ((unsigned)(cc[i] - b * BRANGE) << 16) | (unsigned)rr[i];
            u.adr[p] = (slot < CAPB) ? (unsigned)(b * CAPB + slot) : 0xFFFFFFFFu;
        }
    }
    __syncthreads();

    // coalesced compact stream-out (~49 B per-bucket runs; R5 showed the
    // scattered-cell alternative costs 8x write amplification -> keep this)
    const int total = s_total;
    for (int p = t; p < total; p += NTHR) {
        const unsigned a = u.adr[p];
        if (a != 0xFFFFFFFFu) recs[a] = u.buf[p];
    }
}

// Degree count (uint4 record stream) -> dinv -> z0 = dinv * mv.
__global__ void __launch_bounds__(NTHR) k_prep(
    const int* __restrict__ gcur, const unsigned* __restrict__ recs,
    const float* __restrict__ mv, float* __restrict__ dinv,
    float* __restrict__ z0)
{
    __shared__ int s_deg[BRANGE];
    const int t = threadIdx.x;
    const int blk = blockIdx.x;
    if (t < BRANGE) s_deg[t] = 0;
    __syncthreads();

    const int sz = min(gcur[blk], CAPB);
    const int szw = (sz + 3) >> 2;               // <= 1024: single pass
    const uint4* rb4 = (const uint4*)(recs + (size_t)blk * CAPB);
    if (t < szw) {
        const uint4 r = rb4[t];
        const int b4 = t << 2;
        if (b4 + 0 < sz) atomicAdd(&s_deg[r.x >> 16], 1);
        if (b4 + 1 < sz) atomicAdd(&s_deg[r.y >> 16], 1);
        if (b4 + 2 < sz) atomicAdd(&s_deg[r.z >> 16], 1);
        if (b4 + 3 < sz) atomicAdd(&s_deg[r.w >> 16], 1);
    }
    __syncthreads();

    if (t < BRANGE) {
        const int node = blk * BRANGE + t;
        if (node < N_NODES) {
            const float d = rsqrtf((float)(s_deg[t] + 1));  // +1 self loop
            dinv[node] = d;
            z0[node] = d * mv[node];
        }
    }
}

// Hop: stream own records (uint4, 4 independent cached gathers in flight),
// LDS f32 accumulate over 196 owned nodes, finalize with self term.
//   FINAL=false: out[i] = dinv^2 * (z[i] + sum)      (emits next z)
//   FINAL=true : out[i] = dinv   * (z[i] + sum) + b
template <bool FINAL>
__global__ void __launch_bounds__(NTHR) k_hop(
    const int* __restrict__ gcur, const unsigned* __restrict__ recs,
    const float* __restrict__ dinv, const float* __restrict__ zin,
    float* __restrict__ out, const float* __restrict__ bptr)
{
    __shared__ float s_acc[BRANGE];
    const int t = threadIdx.x;
    const int blk = blockIdx.x;
    if (t < BRANGE) s_acc[t] = 0.0f;
    __syncthreads();

    const int sz  = min(gcur[blk], CAPB);
    const int sz4 = sz >> 2;
    const uint4* rb4 = (const uint4*)(recs + (size_t)blk * CAPB);
    for (int e = t; e < sz4; e += NTHR) {
        const uint4 r = rb4[e];
        const float v0 = zin[r.x & 0xFFFFu];
        const float v1 = zin[r.y & 0xFFFFu];
        const float v2 = zin[r.z & 0xFFFFu];
        const float v3 = zin[r.w & 0xFFFFu];
        atomicAdd(&s_acc[r.x >> 16], v0);
        atomicAdd(&s_acc[r.y >> 16], v1);
        atomicAdd(&s_acc[r.z >> 16], v2);
        atomicAdd(&s_acc[r.w >> 16], v3);
    }
    if (t < (sz & 3)) {
        const unsigned r = recs[(size_t)blk * CAPB + (sz4 << 2) + t];
        atomicAdd(&s_acc[r >> 16], zin[r & 0xFFFFu]);
    }
    __syncthreads();

    if (t < BRANGE) {
        const int node = blk * BRANGE + t;
        if (node < N_NODES) {
            const float d = dinv[node];
            const float v = zin[node] + s_acc[t];
            out[node] = FINAL ? (d * v + bptr[0]) : (d * d * v);
        }
    }
}

// ---------------- launch ----------------

extern "C" void kernel_launch(void* const* d_in, const int* in_sizes, int n_in,
                              void* d_out, int out_size, void* d_ws, size_t ws_size,
                              hipStream_t stream) {
    const float* x  = (const float*)d_in[0];   // [N, 64]
    const int*   ei = (const int*)d_in[1];     // [2, E]
    const float* W  = (const float*)d_in[2];   // [1, 64]
    const float* b  = (const float*)d_in[3];   // [1]
    float* out = (float*)d_out;                // [N]

    const int* row = ei;                       // sources
    const int* col = ei + N_EDGES;             // destinations

    // ws: gcur[256] | recs[NBUCK*CAPB u32] (4 MB) | mv[N] | dinv[N] | z0[N] | z1[N]
    int*      gcur = (int*)d_ws;
    unsigned* recs = (unsigned*)(gcur + NBUCK);
    float*    mv   = (float*)(recs + (size_t)NBUCK * CAPB);
    float*    dinv = mv + N_NODES;
    float*    z0   = dinv + N_NODES;
    float*    z1   = z0 + N_NODES;

    // zero bucket cursors (capture-safe DMA memset)
    hipMemsetAsync(gcur, 0, NBUCK * sizeof(int), stream);

    // Split pipeline (R1-proven faster than fused+grid-barriers): dispatch
    // boundaries provide cross-XCD coherence for free -> all plain cached ops.
    k_bucketize<<<dim3(NBUCK), dim3(NTHR), 0, stream>>>(row, col, x, W, gcur, recs, mv);
    k_prep<<<dim3(NBUCK), dim3(NTHR), 0, stream>>>(gcur, recs, mv, dinv, z0);
    k_hop<false><<<dim3(NBUCK), dim3(NTHR), 0, stream>>>(gcur, recs, dinv, z0, z1, nullptr);
    k_hop<false><<<dim3(NBUCK), dim3(NTHR), 0, stream>>>(gcur, recs, dinv, z1, z0, nullptr);
    k_hop<true ><<<dim3(NBUCK), dim3(NTHR), 0, stream>>>(gcur, recs, dinv, z0, out, b);
}